// Round 8
// baseline (268.922 us; speedup 1.0000x reference)
//
#include <hip/hip_runtime.h>

#define HD 100     // hidden width
#define HPAIRS 50  // hidden pairs total
#define HPW 25     // pairs per wave-half
#define DD 6       // state dim
#define TT 8       // timesteps
#define WPS 32     // packed pair-row stride (floats) = 128B

typedef float v2f __attribute__((ext_vector_type(2)));

__device__ __forceinline__ v2f splat2(float s) { v2f r; r.x = s; r.y = s; return r; }
__device__ __forceinline__ v2f fma2(v2f a, v2f b, v2f c) {
    return __builtin_elementwise_fma(a, b, c);
}

// Pack pair rows: [b1(h),b1(h+1) | W1[h][d],W1[h+1][d] d=0..5 | W2[d][h],W2[d][h+1] d=0..5 | pad6]
__global__ void pack_weights_kernel(const float* __restrict__ W1,
                                    const float* __restrict__ b1,
                                    const float* __restrict__ W2,
                                    float* __restrict__ wp)
{
    int p = blockIdx.x * blockDim.x + threadIdx.x;
    if (p >= HPAIRS) return;
    const int h = 2 * p;
    float* row = wp + (size_t)p * WPS;
    row[0] = b1[h];
    row[1] = b1[h + 1];
    #pragma unroll
    for (int d = 0; d < DD; ++d) {
        row[2 + 2 * d]  = W1[h * DD + d];
        row[3 + 2 * d]  = W1[(h + 1) * DD + d];
        row[14 + 2 * d] = W2[d * HD + h];
        row[15 + 2 * d] = W2[d * HD + h + 1];
    }
    #pragma unroll
    for (int i = 26; i < WPS; ++i) row[i] = 0.0f;
}

// exp-based tanh (empirically best on gfx950; trans pipe overlaps VALU issue)
__device__ __forceinline__ v2f tanh2(v2f x) {
    v2f z = x * splat2(2.885390081777927f); // 2*log2(e)
    v2f e;
    e.x = __builtin_amdgcn_exp2f(z.x);
    e.y = __builtin_amdgcn_exp2f(z.y);
    v2f ep = e + splat2(1.0f);
    v2f r;
    r.x = __builtin_amdgcn_rcpf(ep.x);
    r.y = __builtin_amdgcn_rcpf(ep.y);
    return fma2(splat2(-2.0f), r, splat2(1.0f));
}

// Block = 256 threads = 4 waves. Waves (0,1) share samples 0..63 of the block,
// waves (2,3) share samples 64..127; within a pair, half=0 does h 0..49 and
// half=1 does h 50..99. Partial k exchanged via LDS, 1 barrier per feval.
// NO min-waves clamp: R7's (256,8) forced VGPR=32 -> 40MB scratch spill.
__global__ __launch_bounds__(256) void ODEModel_74732430950754_kernel(
    const float* __restrict__ inp, const float* __restrict__ wp,
    const float* __restrict__ b2, const float* __restrict__ Wl,
    const float* __restrict__ bl, float* __restrict__ out, int B)
{
    __shared__ float xch[2][DD][2][128];  // [buf][d][half][sample-slot] = 12 KB

    const int tid  = threadIdx.x;
    const int wid  = tid >> 6;
    const int lane = tid & 63;
    const int half = wid & 1;                       // hidden-dim half (0/1)
    const int sl   = ((wid >> 1) << 6) | lane;      // sample slot [0,128)
    const int oidx = blockIdx.x * 128 + sl;

    // wave-uniform loads -> SGPRs (no VGPR cost)
    float b2v[DD], wl[DD];
    #pragma unroll
    for (int d = 0; d < DD; ++d) { b2v[d] = b2[d]; wl[d] = Wl[d]; }
    const float blv = bl[0];

    float y[DD];
    #pragma unroll
    for (int d = 0; d < DD; ++d)
        y[d] = inp[(size_t)oidx * (TT * DD) + (TT - 1) * DD + d];

    const float* __restrict__ wbase = wp + (size_t)(half * HPW) * WPS;

    float acc[DD], yt[DD], k[DD];

    auto feval = [&](const float (&yin)[DD], float (&kout)[DD], int buf) {
        v2f kk[DD];
        #pragma unroll
        for (int d = 0; d < DD; ++d) {
            kk[d].x = (half == 0) ? b2v[d] : 0.0f;
            kk[d].y = 0.0f;
        }
        #pragma unroll 5
        for (int p = 0; p < HPW; ++p) {
            const v2f* __restrict__ rp =
                reinterpret_cast<const v2f*>(wbase + (size_t)p * WPS);
            v2f pre = rp[0];
            #pragma unroll
            for (int d = 0; d < DD; ++d)
                pre = fma2(splat2(yin[d]), rp[1 + d], pre);  // op_sel: 1 VGPR feeds both lanes
            v2f t = tanh2(pre);
            #pragma unroll
            for (int d = 0; d < DD; ++d) kk[d] = fma2(t, rp[7 + d], kk[d]);
        }
        // exchange partials (conflict-free: lane stride = 4B)
        #pragma unroll
        for (int d = 0; d < DD; ++d) xch[buf][d][half][sl] = kk[d].x + kk[d].y;
        __syncthreads();
        #pragma unroll
        for (int d = 0; d < DD; ++d)
            kout[d] = (kk[d].x + kk[d].y) + xch[buf][d][half ^ 1][sl];
    };

    // One RK4 step, h = 1
    feval(y, k, 0);   // k1
    #pragma unroll
    for (int d = 0; d < DD; ++d) {
        acc[d] = k[d];
        yt[d]  = __builtin_fmaf(0.5f, k[d], y[d]);
    }
    feval(yt, k, 1);  // k2
    #pragma unroll
    for (int d = 0; d < DD; ++d) {
        acc[d] = __builtin_fmaf(2.0f, k[d], acc[d]);
        yt[d]  = __builtin_fmaf(0.5f, k[d], y[d]);
    }
    feval(yt, k, 0);  // k3
    #pragma unroll
    for (int d = 0; d < DD; ++d) {
        acc[d] = __builtin_fmaf(2.0f, k[d], acc[d]);
        yt[d]  = y[d] + k[d];
    }
    feval(yt, k, 1);  // k4
    #pragma unroll
    for (int d = 0; d < DD; ++d)
        y[d] = __builtin_fmaf(1.0f / 6.0f, acc[d] + k[d], y[d]);

    float o = blv;
    #pragma unroll
    for (int d = 0; d < DD; ++d) o = __builtin_fmaf(y[d], wl[d], o);
    if (half == 0) out[oidx] = o;
}

extern "C" void kernel_launch(void* const* d_in, const int* in_sizes, int n_in,
                              void* d_out, int out_size, void* d_ws, size_t ws_size,
                              hipStream_t stream) {
    const float* inp = (const float*)d_in[0];
    const float* W1  = (const float*)d_in[1];
    const float* b1  = (const float*)d_in[2];
    const float* W2  = (const float*)d_in[3];
    const float* b2  = (const float*)d_in[4];
    const float* Wl  = (const float*)d_in[5];
    const float* bl  = (const float*)d_in[6];
    float* out = (float*)d_out;
    float* wp  = (float*)d_ws;   // needs HPAIRS*WPS*4 = 6.4 KB

    const int B = in_sizes[0] / (TT * DD);

    hipLaunchKernelGGL(pack_weights_kernel, dim3(1), dim3(64), 0, stream, W1, b1, W2, wp);

    const int blocks = (B + 127) / 128;  // 128 samples per block (B = 262144: exact)
    hipLaunchKernelGGL(ODEModel_74732430950754_kernel, dim3(blocks), dim3(256), 0, stream,
                       inp, wp, b2, Wl, bl, out, B);
}

// Round 9
// 130.290 us; speedup vs baseline: 2.0640x; 2.0640x over previous
//
#include <hip/hip_runtime.h>

#define HD 100     // hidden width
#define HPAIRS 50  // hidden pairs total
#define HPW 25     // pairs per wave-half
#define DD 6       // state dim
#define TT 8       // timesteps
#define WPS 32     // packed pair-row stride (floats) = 128B

typedef float v2f __attribute__((ext_vector_type(2)));

__device__ __forceinline__ v2f splat2(float s) { v2f r; r.x = s; r.y = s; return r; }
__device__ __forceinline__ v2f fma2(v2f a, v2f b, v2f c) {
    return __builtin_elementwise_fma(a, b, c);
}

// Pack pair rows: [b1(h),b1(h+1) | W1[h][d],W1[h+1][d] d=0..5 | W2[d][h],W2[d][h+1] d=0..5 | pad6]
__global__ void pack_weights_kernel(const float* __restrict__ W1,
                                    const float* __restrict__ b1,
                                    const float* __restrict__ W2,
                                    float* __restrict__ wp)
{
    int p = blockIdx.x * blockDim.x + threadIdx.x;
    if (p >= HPAIRS) return;
    const int h = 2 * p;
    float* row = wp + (size_t)p * WPS;
    row[0] = b1[h];
    row[1] = b1[h + 1];
    #pragma unroll
    for (int d = 0; d < DD; ++d) {
        row[2 + 2 * d]  = W1[h * DD + d];
        row[3 + 2 * d]  = W1[(h + 1) * DD + d];
        row[14 + 2 * d] = W2[d * HD + h];
        row[15 + 2 * d] = W2[d * HD + h + 1];
    }
    #pragma unroll
    for (int i = 26; i < WPS; ++i) row[i] = 0.0f;
}

// exp-based tanh (empirically best on gfx950; trans pipe overlaps VALU issue)
__device__ __forceinline__ v2f tanh2(v2f x) {
    v2f z = x * splat2(2.885390081777927f); // 2*log2(e)
    v2f e;
    e.x = __builtin_amdgcn_exp2f(z.x);
    e.y = __builtin_amdgcn_exp2f(z.y);
    v2f ep = e + splat2(1.0f);
    v2f r;
    r.x = __builtin_amdgcn_rcpf(ep.x);
    r.y = __builtin_amdgcn_rcpf(ep.y);
    return fma2(splat2(-2.0f), r, splat2(1.0f));
}

// Block = 256 threads = 4 waves. Waves (0,1) share samples 0..63 of the block,
// waves (2,3) share samples 64..127; within a pair, half=0 does h 0..49 and
// half=1 does h 50..99. Partial k exchanged via LDS, 1 barrier per feval.
// half goes through readfirstlane so the weight pointer is PROVABLY wave-uniform
// -> s_load path (R8 lost it: SGPR 96->32, VMEM-stall-bound at 17% VALUBusy).
__global__ __launch_bounds__(256) void ODEModel_74732430950754_kernel(
    const float* __restrict__ inp, const float* __restrict__ wp,
    const float* __restrict__ b2, const float* __restrict__ Wl,
    const float* __restrict__ bl, float* __restrict__ out, int B)
{
    __shared__ float xch[2][DD][2][128];  // [buf][d][half][sample-slot] = 12 KB

    const int tid  = threadIdx.x;
    const int wid  = tid >> 6;
    const int lane = tid & 63;
    // wave-uniform by construction; readfirstlane makes it provable to LLVM
    const int half = __builtin_amdgcn_readfirstlane(wid & 1);
    const int sl   = ((wid >> 1) << 6) | lane;      // sample slot [0,128)
    const int oidx = blockIdx.x * 128 + sl;

    // wave-uniform loads -> SGPRs (no VGPR cost)
    float b2v[DD], wl[DD];
    #pragma unroll
    for (int d = 0; d < DD; ++d) { b2v[d] = b2[d]; wl[d] = Wl[d]; }
    const float blv = bl[0];

    float y[DD];
    #pragma unroll
    for (int d = 0; d < DD; ++d)
        y[d] = inp[(size_t)oidx * (TT * DD) + (TT - 1) * DD + d];

    const float* __restrict__ wbase = wp + (size_t)(half * (HPW * WPS));

    float acc[DD], yt[DD], k[DD];

    auto feval = [&](const float (&yin)[DD], float (&kout)[DD], int buf) {
        v2f kk[DD];
        #pragma unroll
        for (int d = 0; d < DD; ++d) {
            kk[d].x = (half == 0) ? b2v[d] : 0.0f;
            kk[d].y = 0.0f;
        }
        #pragma unroll 5
        for (int p = 0; p < HPW; ++p) {
            const v2f* __restrict__ rp =
                reinterpret_cast<const v2f*>(wbase + (size_t)p * WPS);
            v2f pre = rp[0];
            #pragma unroll
            for (int d = 0; d < DD; ++d)
                pre = fma2(splat2(yin[d]), rp[1 + d], pre);
            v2f t = tanh2(pre);
            #pragma unroll
            for (int d = 0; d < DD; ++d) kk[d] = fma2(t, rp[7 + d], kk[d]);
        }
        // exchange partials (conflict-free: lane stride = 4B)
        #pragma unroll
        for (int d = 0; d < DD; ++d) xch[buf][d][half][sl] = kk[d].x + kk[d].y;
        __syncthreads();
        #pragma unroll
        for (int d = 0; d < DD; ++d)
            kout[d] = (kk[d].x + kk[d].y) + xch[buf][d][half ^ 1][sl];
    };

    // One RK4 step, h = 1
    feval(y, k, 0);   // k1
    #pragma unroll
    for (int d = 0; d < DD; ++d) {
        acc[d] = k[d];
        yt[d]  = __builtin_fmaf(0.5f, k[d], y[d]);
    }
    feval(yt, k, 1);  // k2
    #pragma unroll
    for (int d = 0; d < DD; ++d) {
        acc[d] = __builtin_fmaf(2.0f, k[d], acc[d]);
        yt[d]  = __builtin_fmaf(0.5f, k[d], y[d]);
    }
    feval(yt, k, 0);  // k3
    #pragma unroll
    for (int d = 0; d < DD; ++d) {
        acc[d] = __builtin_fmaf(2.0f, k[d], acc[d]);
        yt[d]  = y[d] + k[d];
    }
    feval(yt, k, 1);  // k4
    #pragma unroll
    for (int d = 0; d < DD; ++d)
        y[d] = __builtin_fmaf(1.0f / 6.0f, acc[d] + k[d], y[d]);

    float o = blv;
    #pragma unroll
    for (int d = 0; d < DD; ++d) o = __builtin_fmaf(y[d], wl[d], o);
    if (half == 0) out[oidx] = o;
}

extern "C" void kernel_launch(void* const* d_in, const int* in_sizes, int n_in,
                              void* d_out, int out_size, void* d_ws, size_t ws_size,
                              hipStream_t stream) {
    const float* inp = (const float*)d_in[0];
    const float* W1  = (const float*)d_in[1];
    const float* b1  = (const float*)d_in[2];
    const float* W2  = (const float*)d_in[3];
    const float* b2  = (const float*)d_in[4];
    const float* Wl  = (const float*)d_in[5];
    const float* bl  = (const float*)d_in[6];
    float* out = (float*)d_out;
    float* wp  = (float*)d_ws;   // needs HPAIRS*WPS*4 = 6.4 KB

    const int B = in_sizes[0] / (TT * DD);

    hipLaunchKernelGGL(pack_weights_kernel, dim3(1), dim3(64), 0, stream, W1, b1, W2, wp);

    const int blocks = (B + 127) / 128;  // 128 samples per block (B = 262144: exact)
    hipLaunchKernelGGL(ODEModel_74732430950754_kernel, dim3(blocks), dim3(256), 0, stream,
                       inp, wp, b2, Wl, bl, out, B);
}